// Round 12
// baseline (482.193 us; speedup 1.0000x reference)
//
#include <hip/hip_runtime.h>

#define N_NODES 100000
#define N_EDGES 1200000
#define D 64
#define NUM_LAYERS 3

#define NB 196          // coarse buckets
#define BSZ 512         // nodes per bucket (NB*BSZ = 100352 >= N_NODES)
#define NPAD (NB * BSZ) // padded node count (100352, multiple of 128)
#define CHUNK 4096      // edges per partition block
#define NCHUNK ((N_EDGES + CHUNK - 1) / CHUNK)   // 293
#define ZROW N_NODES    // dummy src row (zeroed) for list padding
#define BSLACK 3592     // per-bucket pad slack: 512*7 + 8 (alignment-safe)
#define HSZ ((size_t)NPAD * 32)   // u16 elems per feature-half block

typedef unsigned int uint;
typedef unsigned short u16;

using short8 = __attribute__((ext_vector_type(8))) short;
using f32x4  = __attribute__((ext_vector_type(4))) float;

static __device__ __forceinline__ float b2f(u16 u) {
    return __uint_as_float(((uint)u) << 16);
}
static __device__ __forceinline__ u16 f2b(float f) {
    uint u = __float_as_uint(f);
    return (u16)((u + 0x7FFFu + ((u >> 16) & 1u)) >> 16);
}
static __device__ __forceinline__ float blo(uint v) {
    return __uint_as_float(v << 16);
}
static __device__ __forceinline__ float bhi(uint v) {
    return __uint_as_float(v & 0xFFFF0000u);
}

// ---- P1: coarse bucket histograms (dst and src) via LDS ----
__global__ __launch_bounds__(256) void hist_kernel(const int* __restrict__ src,
        const int* __restrict__ dst, int* __restrict__ cnt2, int E) {
    __shared__ int hD[NB], hS[NB];
    for (int i = threadIdx.x; i < NB; i += 256) { hD[i] = 0; hS[i] = 0; }
    __syncthreads();
    int i = blockIdx.x * 256 + threadIdx.x;
    int stride = gridDim.x * 256;
    for (; i < E; i += stride) {
        atomicAdd(&hD[((unsigned)dst[i]) >> 9], 1);
        atomicAdd(&hS[((unsigned)src[i]) >> 9], 1);
    }
    __syncthreads();
    for (int i2 = threadIdx.x; i2 < NB; i2 += 256) {
        if (hD[i2]) atomicAdd(&cnt2[i2], hD[i2]);
        if (hS[i2]) atomicAdd(&cnt2[NB + i2], hS[i2]);
    }
}

// ---- P2a: scan bucket counts -> bases + cursors ----
__global__ __launch_bounds__(256) void scanb_kernel(const int* __restrict__ cnt2,
        int* __restrict__ base2, int* __restrict__ curs2) {
    __shared__ int buf[256];
    int t = threadIdx.x;
    for (int arr = 0; arr < 2; ++arr) {
        int v = (t < NB) ? cnt2[arr * NB + t] : 0;
        buf[t] = v;
        __syncthreads();
        for (int off = 1; off < 256; off <<= 1) {
            int u = (t >= off) ? buf[t - off] : 0;
            __syncthreads();
            buf[t] += u;
            __syncthreads();
        }
        int excl = buf[t] - v;
        if (t < NB) {
            base2[arr * (NB + 1) + t] = excl;
            curs2[arr * NB + t] = excl;
        }
        if (t == NB - 1) base2[arr * (NB + 1) + NB] = buf[t];
        __syncthreads();
    }
}

// ---- P2b: partition edges into coarse buckets (LDS-staged chunks) ----
__global__ __launch_bounds__(256) void part_kernel(const int* __restrict__ src,
        const int* __restrict__ dst, int* __restrict__ cursD, int* __restrict__ cursS,
        int* __restrict__ dstPart, u16* __restrict__ srcPart, int E) {
    __shared__ int eS[CHUNK], eT[CHUNK];
    __shared__ int hD[NB], hS[NB], bD[NB], bS[NB];
    int e0 = blockIdx.x * CHUNK;
    int n = min(CHUNK, E - e0);
    for (int i = threadIdx.x; i < NB; i += 256) { hD[i] = 0; hS[i] = 0; }
    for (int i = threadIdx.x; i < n; i += 256) { eS[i] = src[e0 + i]; eT[i] = dst[e0 + i]; }
    __syncthreads();
    for (int i = threadIdx.x; i < n; i += 256) {
        atomicAdd(&hD[((unsigned)eT[i]) >> 9], 1);
        atomicAdd(&hS[((unsigned)eS[i]) >> 9], 1);
    }
    __syncthreads();
    for (int i = threadIdx.x; i < NB; i += 256) {
        bD[i] = hD[i] ? atomicAdd(&cursD[i], hD[i]) : 0;
        bS[i] = hS[i] ? atomicAdd(&cursS[i], hS[i]) : 0;
        hD[i] = 0; hS[i] = 0;          // reuse as local cursors
    }
    __syncthreads();
    for (int i = threadIdx.x; i < n; i += 256) {
        int s = eS[i], t = eT[i];
        int kb = ((unsigned)t) >> 9;
        int pos = bD[kb] + atomicAdd(&hD[kb], 1);
        dstPart[pos] = ((t & 511) << 20) | s;
        kb = ((unsigned)s) >> 9;
        pos = bS[kb] + atomicAdd(&hS[kb], 1);
        srcPart[pos] = (u16)(s & 511);
    }
}

// ---- P3a: per-bucket CSR, lists padded to multiples of 8 (dummy = ZROW) ----
__global__ __launch_bounds__(256) void csr_kernel(const int* __restrict__ baseD,
        const int* __restrict__ dstPart, int* __restrict__ rowptr,
        int* __restrict__ rowend, int* __restrict__ cv) {
    __shared__ int cnt[BSZ], curs[BSZ], psum[256];
    int b = blockIdx.x, t = threadIdx.x;
    int node0 = b * BSZ;
    int eb = baseD[b], ee = baseD[b + 1];
    int padbase = ((eb + 7) & ~7) + b * BSLACK;   // 8-aligned, non-overlapping
    for (int i = t; i < BSZ; i += 256) cnt[i] = 0;
    __syncthreads();
    for (int e = eb + t; e < ee; e += 256)
        atomicAdd(&cnt[((unsigned)dstPart[e]) >> 20], 1);
    __syncthreads();
    int c0 = cnt[2 * t], c1 = cnt[2 * t + 1];
    int p0 = (c0 + 7) & ~7, p1 = (c1 + 7) & ~7;
    psum[t] = p0 + p1;
    __syncthreads();
    for (int off = 1; off < 256; off <<= 1) {
        int u = (t >= off) ? psum[t - off] : 0;
        __syncthreads();
        psum[t] += u;
        __syncthreads();
    }
    int excl = psum[t] - p0 - p1;
    int start0 = padbase + excl;
    int start1 = start0 + p0;
    curs[2 * t] = start0;
    curs[2 * t + 1] = start1;
    int n0 = node0 + 2 * t;
    if (n0 < N_NODES)     { rowptr[n0]     = start0; rowend[n0]     = start0 + p0; }
    if (n0 + 1 < N_NODES) { rowptr[n0 + 1] = start1; rowend[n0 + 1] = start1 + p1; }
    __syncthreads();
    for (int e = eb + t; e < ee; e += 256) {
        int p = dstPart[e];
        int loc = ((unsigned)p) >> 20;
        int pos = atomicAdd(&curs[loc], 1);
        cv[pos] = p & 0xFFFFF;
    }
    __syncthreads();
    // fill dummy tail slots
    for (int q = c0; q < p0; ++q) cv[start0 + q] = ZROW;
    for (int q = c1; q < p1; ++q) cv[start1 + q] = ZROW;
}

// ---- P3b: per-bucket src-degree histogram -> dinv ----
__global__ __launch_bounds__(256) void degs_kernel(const int* __restrict__ baseS,
        const u16* __restrict__ srcPart, float* __restrict__ dinv) {
    __shared__ int cnt[BSZ];
    int b = blockIdx.x, t = threadIdx.x;
    int eb = baseS[b], ee = baseS[b + 1];
    for (int i = t; i < BSZ; i += 256) cnt[i] = 0;
    __syncthreads();
    for (int e = eb + t; e < ee; e += 256)
        atomicAdd(&cnt[srcPart[e]], 1);
    __syncthreads();
    for (int i = t; i < BSZ; i += 256) {
        int node = b * BSZ + i;
        if (node < N_NODES) {
            int d = cnt[i];
            dinv[node] = (d > 0) ? rsqrtf((float)d) : 0.0f;
        }
    }
}

// ---- W -> bf16 fragments in MFMA order, all layers once ----
// fid = ((l*2 + wn)*6 + kt)*2 + ni ; element = fid*512 + lane*8 + j
// skip-fold: for l>0 add identity (out += Tx0, i.e. W0' = W0 + I)
__global__ __launch_bounds__(256) void wprep_kernel(const float* __restrict__ W,
        u16* __restrict__ Wb) {
    int i = blockIdx.x * 256 + threadIdx.x;
    if (i >= 72 * 512) return;
    int j = i & 7;
    int lane = (i >> 3) & 63;
    int fid = i >> 9;
    int ni = fid & 1;
    int t = fid >> 1;
    int kt = t % 6;
    int t2 = t / 6;
    int wn = t2 & 1;
    int l = t2 >> 1;
    int k = kt * 32 + (lane >> 4) * 8 + j;
    int col = wn * 32 + ni * 16 + (lane & 15);
    float v = W[((size_t)l * 192 + k) * 64 + col];
    if (l > 0 && k == col) v += 1.0f;   // skip folded into W0
    Wb[i] = f2b(v);
}

// ---- zero the ZROW rows (both halves) of the 3 blocked gather sources ----
__global__ void zrow_kernel(u16* a, u16* b, u16* c) {
    int i = threadIdx.x;           // 0..191: buf(3) x half(2) x feat(32)
    if (i >= 192) return;
    u16* buf = (i < 64) ? a : (i < 128) ? b : c;
    int r = i & 63;
    int q = r >> 5, fl = r & 31;
    buf[(size_t)q * HSZ + (size_t)ZROW * 32 + fl] = 0;
}

// ---- x -> gx = dinv * x (bf16, blocked [2][NPAD][32]) ----
__global__ __launch_bounds__(256) void cvt_kernel(const float* __restrict__ x,
        const float* __restrict__ dinv, u16* __restrict__ gx2, int nvec) {
    int i = blockIdx.x * blockDim.x + threadIdx.x;
    if (i >= nvec) return;
    float4 v = ((const float4*)x)[i];
    int node = i >> 4;
    int c = (i & 15) * 4;
    float dv = dinv[node];
    uint2 b;
    b.x = (uint)f2b(v.x * dv) | ((uint)f2b(v.y * dv) << 16);
    b.y = (uint)f2b(v.z * dv) | ((uint)f2b(v.w * dv) << 16);
    *(uint2*)(gx2 + (size_t)(c >> 5) * HSZ + (size_t)node * 32 + (c & 31)) = b;
}

// ---- propagate, feature-half split + quad-edge groups ----
// grid = 2*G2 blocks; phase q = (bid >= G2) selects feature half.
// wave = one node; 4 groups of 16 lanes (grp = lane>>4), each group one edge;
// lane li = lane&15 covers features {2li, 2li+1} of half q (one uint load).
// Combine across groups via shfl_xor(16)+shfl_xor(32); group 0 stores.
__global__ __launch_bounds__(256) void gather_kernel(const int* __restrict__ rowptr,
        const int* __restrict__ rowend, const int* __restrict__ cv,
        const u16* __restrict__ g2, const float* __restrict__ dinv,
        u16* __restrict__ trow, u16* __restrict__ gq2, int n) {
    const int G2 = (N_NODES + 3) / 4;
    int bid = blockIdx.x;
    int q = (bid >= G2) ? 1 : 0;
    int nb = q ? bid - G2 : bid;
    int lane = threadIdx.x & 63;
    int li = lane & 15;        // feature-pair index
    int grp = lane >> 4;       // edge group 0..3
    int node = __builtin_amdgcn_readfirstlane(nb * 4 + (threadIdx.x >> 6));
    if (node >= n) return;
    const u16* __restrict__ gq = g2 + (size_t)q * HSZ;

    int p = rowptr[node];
    const int pe = rowend[node];
    float s0 = 0.f, s1 = 0.f;

#define SEL(c) ((grp == 0) ? (c).x : (grp == 1) ? (c).y : (grp == 2) ? (c).z : (c).w)
#define LD(s) (*(const uint*)(gq + (size_t)(s) * 32 + li * 2))
    if (pe - p == 16) {
        int4 c0 = *(const int4*)(cv + p);
        int4 c1 = *(const int4*)(cv + p + 4);
        int4 c2 = *(const int4*)(cv + p + 8);
        int4 c3 = *(const int4*)(cv + p + 12);
        uint v0 = LD(SEL(c0));
        uint v1 = LD(SEL(c1));
        uint v2 = LD(SEL(c2));
        uint v3 = LD(SEL(c3));
        s0 = (blo(v0) + blo(v1)) + (blo(v2) + blo(v3));
        s1 = (bhi(v0) + bhi(v1)) + (bhi(v2) + bhi(v3));
    } else if (pe > p) {
        int4 ca = *(const int4*)(cv + p);
        int4 cb = *(const int4*)(cv + p + 4);
        for (;;) {
            int np = p + 8;
            bool more = np < pe;
            int4 na, nb4;
            if (more) {                    // prefetch next round's cv early
                na  = *(const int4*)(cv + np);
                nb4 = *(const int4*)(cv + np + 4);
            }
            uint v0 = LD(SEL(ca));
            uint v1 = LD(SEL(cb));
            s0 += blo(v0) + blo(v1);
            s1 += bhi(v0) + bhi(v1);
            if (!more) break;
            ca = na; cb = nb4; p = np;
        }
    }
#undef LD
#undef SEL

    s0 += __shfl_xor(s0, 16);
    s0 += __shfl_xor(s0, 32);
    s1 += __shfl_xor(s1, 16);
    s1 += __shfl_xor(s1, 32);

    if (grp == 0) {
        float dv = dinv[node];
        float v0 = -dv * s0;
        float v1 = -dv * s1;
        uint pk = (uint)f2b(v0) | ((uint)f2b(v1) << 16);
        *(uint*)(trow + (size_t)node * 64 + q * 32 + li * 2) = pk;
        if (gq2) {
            uint pg = (uint)f2b(dv * v0) | ((uint)f2b(dv * v1) << 16);
            *(uint*)(gq2 + (size_t)q * HSZ + (size_t)node * 32 + li * 2) = pg;
        }
    }
}

// ---- MFMA epilogue: O = [Tx0|Tx1|2*Tx2-Tx0] @ Wcat' + b, relu (skip folded in W) ----
template<int INPF32>
__global__ __launch_bounds__(256) void cheb_mfma_kernel(
        const float* __restrict__ x,      // f32 input (layer 0)
        const u16* __restrict__ inp,      // bf16 h_prev (layers > 0), row-major
        const u16* __restrict__ t1, const u16* __restrict__ t2,
        const u16* __restrict__ Wbl,      // layer's fragment-ordered bf16 weights
        const float* __restrict__ bias, const float* __restrict__ dinv,
        u16* __restrict__ outb, u16* __restrict__ goutb2, float* __restrict__ outf,
        int writeScaled, int outF32) {
    const int tid = threadIdx.x;
    const int lane = tid & 63;
    const int w = tid >> 6;
    const int wm = w & 1, wn = w >> 1;
    const int l15 = lane & 15;
    const int l4 = lane >> 4;        // 0..3
    const int koff = l4 * 8;

    const int mbase = blockIdx.x * 64 + wm * 32;
    const int nbase = wn * 32;

    // ---- fragment-ordered weight preload: 12 x 16B vector loads ----
    short8 Bf[6][2];
#pragma unroll
    for (int kt = 0; kt < 6; ++kt)
#pragma unroll
        for (int ni = 0; ni < 2; ++ni)
            Bf[kt][ni] = *(const short8*)(Wbl + (size_t)(((wn * 6 + kt) * 2) + ni) * 512 + lane * 8);

    // ---- hoist ALL A-source loads (issue before any convert/MFMA) ----
    short8 T1[2][2], T2[2][2], Fi[2][2];
    float4 Xf[2][2][2];
#pragma unroll
    for (int mi = 0; mi < 2; ++mi) {
        int row = mbase + mi * 16 + l15;
        int rowc = min(row, N_NODES - 1);   // clamp for exact-size f32 x
#pragma unroll
        for (int half = 0; half < 2; ++half) {
            T1[mi][half] = *(const short8*)(t1 + (size_t)row * 64 + half * 32 + koff);
            T2[mi][half] = *(const short8*)(t2 + (size_t)row * 64 + half * 32 + koff);
            if (INPF32) {
                const float* p = x + (size_t)rowc * 64 + half * 32 + koff;
                Xf[mi][half][0] = *(const float4*)p;
                Xf[mi][half][1] = *(const float4*)(p + 4);
            } else {
                Fi[mi][half] = *(const short8*)(inp + (size_t)row * 64 + half * 32 + koff);
            }
        }
    }

    float bj0 = bias[nbase + l15];
    float bj1 = bias[nbase + 16 + l15];

    f32x4 acc[2][2];
#pragma unroll
    for (int mi = 0; mi < 2; ++mi)
#pragma unroll
        for (int ni = 0; ni < 2; ++ni)
#pragma unroll
            for (int r = 0; r < 4; ++r) acc[mi][ni][r] = 0.0f;

#pragma unroll
    for (int kt = 0; kt < 6; ++kt) {
        short8 Af[2];
#pragma unroll
        for (int mi = 0; mi < 2; ++mi) {
            short8 a;
            if (kt < 2) {
                if (INPF32) {
                    const float* p = (const float*)&Xf[mi][kt][0];
#pragma unroll
                    for (int j = 0; j < 8; ++j) a[j] = (short)f2b(p[j]);
                } else {
                    a = Fi[mi][kt];
                }
            } else if (kt < 4) {
                a = T1[mi][kt - 2];
            } else {
                short8 a2 = T2[mi][kt - 4];
                if (INPF32) {
                    const float* p = (const float*)&Xf[mi][kt - 4][0];
#pragma unroll
                    for (int j = 0; j < 8; ++j)
                        a[j] = (short)f2b(fmaf(2.0f, b2f((u16)a2[j]), -p[j]));
                } else {
                    short8 ai = Fi[mi][kt - 4];
#pragma unroll
                    for (int j = 0; j < 8; ++j)
                        a[j] = (short)f2b(fmaf(2.0f, b2f((u16)a2[j]), -b2f((u16)ai[j])));
                }
            }
            Af[mi] = a;
        }
#pragma unroll
        for (int mi = 0; mi < 2; ++mi)
#pragma unroll
            for (int ni = 0; ni < 2; ++ni)
                acc[mi][ni] = __builtin_amdgcn_mfma_f32_16x16x32_bf16(
                    Af[mi], Bf[kt][ni], acc[mi][ni], 0, 0, 0);
    }

    // ---- epilogue: bias + relu + stores (skip folded; dinv vector-loaded) ----
    float4 dvv[2];
    if (writeScaled) {
#pragma unroll
        for (int mi = 0; mi < 2; ++mi)
            dvv[mi] = *(const float4*)(dinv + mbase + mi * 16 + l4 * 4);
    }
#pragma unroll
    for (int mi = 0; mi < 2; ++mi)
#pragma unroll
        for (int r = 0; r < 4; ++r) {
            int node = mbase + mi * 16 + l4 * 4 + r;
            if (node >= N_NODES) continue;
#pragma unroll
            for (int ni = 0; ni < 2; ++ni) {
                int col = nbase + ni * 16 + l15;
                size_t o = (size_t)node * 64 + col;
                float v = acc[mi][ni][r] + (ni ? bj1 : bj0);
                v = fmaxf(v, 0.0f);
                if (outF32) {
                    outf[o] = v;
                } else {
                    outb[o] = f2b(v);
                    if (writeScaled) {
                        float dv = ((const float*)&dvv[mi])[r];
                        goutb2[(size_t)wn * HSZ + (size_t)node * 32 + (col & 31)] =
                            f2b(v * dv);
                    }
                }
            }
        }
}

extern "C" void kernel_launch(void* const* d_in, const int* in_sizes, int n_in,
                              void* d_out, int out_size, void* d_ws, size_t ws_size,
                              hipStream_t stream) {
    const float* x = (const float*)d_in[0];
    const int* ei = (const int*)d_in[1];
    const float* W = (const float*)d_in[2];   // [3,3,64,64]
    const float* b = (const float*)d_in[3];   // [3,64]
    float* out = (float*)d_out;

    const int* src = ei;
    const int* dst = ei + N_EDGES;

    const size_t NDP = (size_t)NPAD * D;
    const size_t CVSZ = (size_t)N_EDGES + 72 + (size_t)NB * BSLACK;  // padded cv entries

    char* w = (char*)d_ws;
    int*   cnt2   = (int*)w;        w += (size_t)512 * 4;
    int*   base2  = (int*)w;        w += (size_t)512 * 4;
    int*   curs2  = (int*)w;        w += (size_t)512 * 4;
    int*   rowptr = (int*)w;        w += (size_t)NPAD * 4;
    int*   rowend = (int*)w;        w += (size_t)NPAD * 4;
    float* dinv   = (float*)w;      w += (size_t)NPAD * 4;
    u16*   Wb     = (u16*)w;        w += (size_t)72 * 512 * 2;
    int*   cv     = (int*)w;        w += ((CVSZ + 63) & ~(size_t)63) * 4;
    u16*   gx     = (u16*)w;        w += NDP * 2;   // blocked [2][NPAD][32]
    u16*   h      = (u16*)w;        w += NDP * 2;   // row-major
    u16*   gh     = (u16*)w;        w += NDP * 2;   // blocked
    u16*   t1     = (u16*)w;        w += NDP * 2;   // row-major
    u16*   gt1    = (u16*)w;        w += NDP * 2;   // blocked
    u16*   t2     = (u16*)w;        w += NDP * 2;   // row-major
    // partition buffers alias gt1/t2 (first real use is after CSR build; ZROW
    // blocked offsets 6.4MB/12.8MB are beyond dstPart's 4.8MB; srcPart = t2 untouched)
    int*   dstPart = (int*)gt1;
    u16*   srcPart = (u16*)t2;

    int* baseD = base2;
    int* baseS = base2 + (NB + 1);
    int* cursD = curs2;
    int* cursS = curs2 + NB;

    // ---- CSR build (bucketed radix partition, LDS atomics, padded lists) ----
    hipMemsetAsync(cnt2, 0, (size_t)(2 * NB) * 4, stream);
    hist_kernel<<<304, 256, 0, stream>>>(src, dst, cnt2, N_EDGES);
    scanb_kernel<<<1, 256, 0, stream>>>(cnt2, base2, curs2);
    part_kernel<<<NCHUNK, 256, 0, stream>>>(src, dst, cursD, cursS, dstPart, srcPart, N_EDGES);
    csr_kernel<<<NB, 256, 0, stream>>>(baseD, dstPart, rowptr, rowend, cv);
    degs_kernel<<<NB, 256, 0, stream>>>(baseS, srcPart, dinv);
    wprep_kernel<<<144, 256, 0, stream>>>(W, Wb);
    zrow_kernel<<<1, 256, 0, stream>>>(gx, gh, gt1);   // after csr/degs (aliasing)
    cvt_kernel<<<(int)(((size_t)N_NODES * D / 4 + 255) / 256), 256, 0, stream>>>(
        x, dinv, gx, (int)((size_t)N_NODES * D / 4));

    const int G2 = (N_NODES + 3) / 4;
    const int gatherBlocks = 2 * G2;     // phase 0 then phase 1
    const int chebBlocks = NPAD / 64;    // 1568 one-tile blocks

    for (int l = 0; l < NUM_LAYERS; ++l) {
        const u16* gin = (l == 0) ? gx : gh;
        gather_kernel<<<gatherBlocks, 256, 0, stream>>>(rowptr, rowend, cv, gin, dinv, t1, gt1, N_NODES);
        gather_kernel<<<gatherBlocks, 256, 0, stream>>>(rowptr, rowend, cv, gt1, dinv, t2, (u16*)0, N_NODES);

        int last = (l == NUM_LAYERS - 1);
        const u16* Wbl = Wb + (size_t)l * 24 * 512;
        const float* bl = b + (size_t)l * D;
        if (l == 0) {
            cheb_mfma_kernel<1><<<chebBlocks, 256, 0, stream>>>(
                x, h, t1, t2, Wbl, bl, dinv, h, gh, out, /*writeScaled=*/!last, /*outF32=*/last);
        } else {
            cheb_mfma_kernel<0><<<chebBlocks, 256, 0, stream>>>(
                x, h, t1, t2, Wbl, bl, dinv, h, gh, out, /*writeScaled=*/!last, /*outF32=*/last);
        }
    }
}

// Round 13
// 326.416 us; speedup vs baseline: 1.4772x; 1.4772x over previous
//
#include <hip/hip_runtime.h>

#define N_NODES 100000
#define N_EDGES 1200000
#define D 64
#define NUM_LAYERS 3

#define NB 196          // coarse buckets
#define BSZ 512         // nodes per bucket (NB*BSZ = 100352 >= N_NODES)
#define NPAD (NB * BSZ) // padded node count (100352, multiple of 128)
#define CHUNK 4096      // edges per partition block
#define NCHUNK ((N_EDGES + CHUNK - 1) / CHUNK)   // 293
#define ZROW N_NODES    // dummy src row (zeroed) for list padding
#define BSLACK 3592     // per-bucket pad slack: 512*7 + 8 (alignment-safe)

typedef unsigned int uint;
typedef unsigned short u16;

using short8 = __attribute__((ext_vector_type(8))) short;
using f32x4  = __attribute__((ext_vector_type(4))) float;

static __device__ __forceinline__ float b2f(u16 u) {
    return __uint_as_float(((uint)u) << 16);
}
static __device__ __forceinline__ u16 f2b(float f) {
    uint u = __float_as_uint(f);
    return (u16)((u + 0x7FFFu + ((u >> 16) & 1u)) >> 16);
}

// ---- P1: coarse bucket histograms (dst and src) via LDS ----
__global__ __launch_bounds__(256) void hist_kernel(const int* __restrict__ src,
        const int* __restrict__ dst, int* __restrict__ cnt2, int E) {
    __shared__ int hD[NB], hS[NB];
    for (int i = threadIdx.x; i < NB; i += 256) { hD[i] = 0; hS[i] = 0; }
    __syncthreads();
    int i = blockIdx.x * 256 + threadIdx.x;
    int stride = gridDim.x * 256;
    for (; i < E; i += stride) {
        atomicAdd(&hD[((unsigned)dst[i]) >> 9], 1);
        atomicAdd(&hS[((unsigned)src[i]) >> 9], 1);
    }
    __syncthreads();
    for (int i2 = threadIdx.x; i2 < NB; i2 += 256) {
        if (hD[i2]) atomicAdd(&cnt2[i2], hD[i2]);
        if (hS[i2]) atomicAdd(&cnt2[NB + i2], hS[i2]);
    }
}

// ---- P2a: scan bucket counts -> bases + cursors ----
__global__ __launch_bounds__(256) void scanb_kernel(const int* __restrict__ cnt2,
        int* __restrict__ base2, int* __restrict__ curs2) {
    __shared__ int buf[256];
    int t = threadIdx.x;
    for (int arr = 0; arr < 2; ++arr) {
        int v = (t < NB) ? cnt2[arr * NB + t] : 0;
        buf[t] = v;
        __syncthreads();
        for (int off = 1; off < 256; off <<= 1) {
            int u = (t >= off) ? buf[t - off] : 0;
            __syncthreads();
            buf[t] += u;
            __syncthreads();
        }
        int excl = buf[t] - v;
        if (t < NB) {
            base2[arr * (NB + 1) + t] = excl;
            curs2[arr * NB + t] = excl;
        }
        if (t == NB - 1) base2[arr * (NB + 1) + NB] = buf[t];
        __syncthreads();
    }
}

// ---- P2b: partition edges into coarse buckets (LDS-staged chunks) ----
__global__ __launch_bounds__(256) void part_kernel(const int* __restrict__ src,
        const int* __restrict__ dst, int* __restrict__ cursD, int* __restrict__ cursS,
        int* __restrict__ dstPart, u16* __restrict__ srcPart, int E) {
    __shared__ int eS[CHUNK], eT[CHUNK];
    __shared__ int hD[NB], hS[NB], bD[NB], bS[NB];
    int e0 = blockIdx.x * CHUNK;
    int n = min(CHUNK, E - e0);
    for (int i = threadIdx.x; i < NB; i += 256) { hD[i] = 0; hS[i] = 0; }
    for (int i = threadIdx.x; i < n; i += 256) { eS[i] = src[e0 + i]; eT[i] = dst[e0 + i]; }
    __syncthreads();
    for (int i = threadIdx.x; i < n; i += 256) {
        atomicAdd(&hD[((unsigned)eT[i]) >> 9], 1);
        atomicAdd(&hS[((unsigned)eS[i]) >> 9], 1);
    }
    __syncthreads();
    for (int i = threadIdx.x; i < NB; i += 256) {
        bD[i] = hD[i] ? atomicAdd(&cursD[i], hD[i]) : 0;
        bS[i] = hS[i] ? atomicAdd(&cursS[i], hS[i]) : 0;
        hD[i] = 0; hS[i] = 0;          // reuse as local cursors
    }
    __syncthreads();
    for (int i = threadIdx.x; i < n; i += 256) {
        int s = eS[i], t = eT[i];
        int kb = ((unsigned)t) >> 9;
        int pos = bD[kb] + atomicAdd(&hD[kb], 1);
        dstPart[pos] = ((t & 511) << 20) | s;
        kb = ((unsigned)s) >> 9;
        pos = bS[kb] + atomicAdd(&hS[kb], 1);
        srcPart[pos] = (u16)(s & 511);
    }
}

// ---- P3a: per-bucket CSR, lists padded to multiples of 8 (dummy = ZROW) ----
__global__ __launch_bounds__(256) void csr_kernel(const int* __restrict__ baseD,
        const int* __restrict__ dstPart, int* __restrict__ rowptr,
        int* __restrict__ rowend, int* __restrict__ cv) {
    __shared__ int cnt[BSZ], curs[BSZ], psum[256];
    int b = blockIdx.x, t = threadIdx.x;
    int node0 = b * BSZ;
    int eb = baseD[b], ee = baseD[b + 1];
    int padbase = ((eb + 7) & ~7) + b * BSLACK;   // 8-aligned, non-overlapping
    for (int i = t; i < BSZ; i += 256) cnt[i] = 0;
    __syncthreads();
    for (int e = eb + t; e < ee; e += 256)
        atomicAdd(&cnt[((unsigned)dstPart[e]) >> 20], 1);
    __syncthreads();
    int c0 = cnt[2 * t], c1 = cnt[2 * t + 1];
    int p0 = (c0 + 7) & ~7, p1 = (c1 + 7) & ~7;
    psum[t] = p0 + p1;
    __syncthreads();
    for (int off = 1; off < 256; off <<= 1) {
        int u = (t >= off) ? psum[t - off] : 0;
        __syncthreads();
        psum[t] += u;
        __syncthreads();
    }
    int excl = psum[t] - p0 - p1;
    int start0 = padbase + excl;
    int start1 = start0 + p0;
    curs[2 * t] = start0;
    curs[2 * t + 1] = start1;
    int n0 = node0 + 2 * t;
    if (n0 < N_NODES)     { rowptr[n0]     = start0; rowend[n0]     = start0 + p0; }
    if (n0 + 1 < N_NODES) { rowptr[n0 + 1] = start1; rowend[n0 + 1] = start1 + p1; }
    __syncthreads();
    for (int e = eb + t; e < ee; e += 256) {
        int p = dstPart[e];
        int loc = ((unsigned)p) >> 20;
        int pos = atomicAdd(&curs[loc], 1);
        cv[pos] = p & 0xFFFFF;
    }
    __syncthreads();
    // fill dummy tail slots
    for (int q = c0; q < p0; ++q) cv[start0 + q] = ZROW;
    for (int q = c1; q < p1; ++q) cv[start1 + q] = ZROW;
}

// ---- P3b: per-bucket src-degree histogram -> s, rs, m arrays ----
// s[r]  = deg>0 ? 1/sqrt(deg) : 1   (feature row scale)
// rs[r] = 1/s[r]                     (epilogue un-scale)
// m[r]  = deg>0 ? -1/deg : 0        (gather output scale = -s*dinv)
__global__ __launch_bounds__(256) void degs_kernel(const int* __restrict__ baseS,
        const u16* __restrict__ srcPart, float* __restrict__ sArr,
        float* __restrict__ rsArr, float* __restrict__ mArr) {
    __shared__ int cnt[BSZ];
    int b = blockIdx.x, t = threadIdx.x;
    int eb = baseS[b], ee = baseS[b + 1];
    for (int i = t; i < BSZ; i += 256) cnt[i] = 0;
    __syncthreads();
    for (int e = eb + t; e < ee; e += 256)
        atomicAdd(&cnt[srcPart[e]], 1);
    __syncthreads();
    for (int i = t; i < BSZ; i += 256) {
        int node = b * BSZ + i;
        if (node < N_NODES) {
            int d = cnt[i];
            float fd = (float)d;
            sArr[node]  = (d > 0) ? rsqrtf(fd) : 1.0f;
            rsArr[node] = (d > 0) ? sqrtf(fd) : 1.0f;
            mArr[node]  = (d > 0) ? (-1.0f / fd) : 0.0f;
        }
    }
}

// ---- W -> bf16 fragments in MFMA order, all layers once ----
// fid = ((l*2 + wn)*6 + kt)*2 + ni ; element = fid*512 + lane*8 + j
// skip-fold: for l>0 add identity (out += h_prev; in scaled space s*h_prev*I)
__global__ __launch_bounds__(256) void wprep_kernel(const float* __restrict__ W,
        u16* __restrict__ Wb) {
    int i = blockIdx.x * 256 + threadIdx.x;
    if (i >= 72 * 512) return;
    int j = i & 7;
    int lane = (i >> 3) & 63;
    int fid = i >> 9;
    int ni = fid & 1;
    int t = fid >> 1;
    int kt = t % 6;
    int t2 = t / 6;
    int wn = t2 & 1;
    int l = t2 >> 1;
    int k = kt * 32 + (lane >> 4) * 8 + j;
    int col = wn * 32 + ni * 16 + (lane & 15);
    float v = W[((size_t)l * 192 + k) * 64 + col];
    if (l > 0 && k == col) v += 1.0f;   // skip folded into W0
    Wb[i] = f2b(v);
}

// ---- zero the ZROW rows of the 3 gather-source buffers ----
__global__ void zrow_kernel(u16* a, u16* b, u16* c) {
    int i = threadIdx.x;           // 0..191
    if (i >= 192) return;
    u16* buf = (i < 64) ? a : (i < 128) ? b : c;
    buf[(size_t)ZROW * D + (i & 63)] = 0;
}

// ---- x -> g0 = s * x (bf16, row-major) ----
__global__ __launch_bounds__(256) void cvt_kernel(const float* __restrict__ x,
        const float* __restrict__ sArr, u16* __restrict__ g0, int nvec) {
    int i = blockIdx.x * blockDim.x + threadIdx.x;
    if (i >= nvec) return;
    float4 v = ((const float4*)x)[i];
    float dv = sArr[i >> 4];
    uint2 b;
    b.x = (uint)f2b(v.x * dv) | ((uint)f2b(v.y * dv) << 16);
    b.y = (uint)f2b(v.z * dv) | ((uint)f2b(v.w * dv) << 16);
    ((uint2*)g0)[i] = b;
}

// ---- propagate (scaled space): outg[t] = m[t] * sum_e g[src_e] ----
// one wave per dst node; padded lists (multiple of 8, 8-aligned starts);
// deep pipeline: 16-edge fast path / pipelined 8-wide general path.
__global__ __launch_bounds__(256) void gather_kernel(const int* __restrict__ rowptr,
        const int* __restrict__ rowend, const int* __restrict__ cv,
        const u16* __restrict__ g, const float* __restrict__ mArr,
        u16* __restrict__ outg, int n) {
    int lane = threadIdx.x & 63;
    int node = __builtin_amdgcn_readfirstlane((int)(blockIdx.x * 4) + (threadIdx.x >> 6));
    if (node >= n) return;
    int p = rowptr[node];
    const int pe = rowend[node];
    const int len = pe - p;
    float a0 = 0.f, a1 = 0.f, a2 = 0.f, a3 = 0.f,
          a4 = 0.f, a5 = 0.f, a6 = 0.f, a7 = 0.f;
    if (len == 16) {
        int4 c0 = *(const int4*)(cv + p);
        int4 c1 = *(const int4*)(cv + p + 4);
        int4 c2 = *(const int4*)(cv + p + 8);
        int4 c3 = *(const int4*)(cv + p + 12);
        float v0  = b2f(g[(size_t)c0.x * D + lane]);
        float v1  = b2f(g[(size_t)c0.y * D + lane]);
        float v2  = b2f(g[(size_t)c0.z * D + lane]);
        float v3  = b2f(g[(size_t)c0.w * D + lane]);
        float v4  = b2f(g[(size_t)c1.x * D + lane]);
        float v5  = b2f(g[(size_t)c1.y * D + lane]);
        float v6  = b2f(g[(size_t)c1.z * D + lane]);
        float v7  = b2f(g[(size_t)c1.w * D + lane]);
        float v8  = b2f(g[(size_t)c2.x * D + lane]);
        float v9  = b2f(g[(size_t)c2.y * D + lane]);
        float v10 = b2f(g[(size_t)c2.z * D + lane]);
        float v11 = b2f(g[(size_t)c2.w * D + lane]);
        float v12 = b2f(g[(size_t)c3.x * D + lane]);
        float v13 = b2f(g[(size_t)c3.y * D + lane]);
        float v14 = b2f(g[(size_t)c3.z * D + lane]);
        float v15 = b2f(g[(size_t)c3.w * D + lane]);
        a0 = (v0 + v8);  a1 = (v1 + v9);  a2 = (v2 + v10); a3 = (v3 + v11);
        a4 = (v4 + v12); a5 = (v5 + v13); a6 = (v6 + v14); a7 = (v7 + v15);
    } else if (len > 0) {
        int4 ca = *(const int4*)(cv + p);
        int4 cb = *(const int4*)(cv + p + 4);
        for (;;) {
            int np = p + 8;
            bool more = np < pe;
            int4 na, nb;
            if (more) {                    // prefetch next round's cv early
                na = *(const int4*)(cv + np);
                nb = *(const int4*)(cv + np + 4);
            }
            a0 += b2f(g[(size_t)ca.x * D + lane]);
            a1 += b2f(g[(size_t)ca.y * D + lane]);
            a2 += b2f(g[(size_t)ca.z * D + lane]);
            a3 += b2f(g[(size_t)ca.w * D + lane]);
            a4 += b2f(g[(size_t)cb.x * D + lane]);
            a5 += b2f(g[(size_t)cb.y * D + lane]);
            a6 += b2f(g[(size_t)cb.z * D + lane]);
            a7 += b2f(g[(size_t)cb.w * D + lane]);
            if (!more) break;
            ca = na; cb = nb; p = np;
        }
    }
    float val = mArr[node] * (((a0 + a1) + (a2 + a3)) + ((a4 + a5) + (a6 + a7)));
    outg[(size_t)node * D + lane] = f2b(val);
}

// ---- MFMA epilogue (scaled space): raw = [g|gt1|2*gt2-g] @ Wcat', then
// v = rs[r]*raw + bias (skip folded in W'), relu; store g_next = s[r]*v
// (or f32 v for the last layer). All operands bf16 row-major.
__global__ __launch_bounds__(256) void cheb_mfma_kernel(
        const u16* __restrict__ gin, const u16* __restrict__ gt1,
        const u16* __restrict__ gt2, const u16* __restrict__ Wbl,
        const float* __restrict__ bias, const float* __restrict__ rsArr,
        const float* __restrict__ sArr,
        u16* __restrict__ outg, float* __restrict__ outf, int last) {
    const int tid = threadIdx.x;
    const int lane = tid & 63;
    const int w = tid >> 6;
    const int wm = w & 1, wn = w >> 1;
    const int l15 = lane & 15;
    const int l4 = lane >> 4;        // 0..3
    const int koff = l4 * 8;

    const int mbase = blockIdx.x * 64 + wm * 32;
    const int nbase = wn * 32;

    // ---- fragment-ordered weight preload: 12 x 16B vector loads ----
    short8 Bf[6][2];
#pragma unroll
    for (int kt = 0; kt < 6; ++kt)
#pragma unroll
        for (int ni = 0; ni < 2; ++ni)
            Bf[kt][ni] = *(const short8*)(Wbl + (size_t)(((wn * 6 + kt) * 2) + ni) * 512 + lane * 8);

    // ---- hoist ALL A-source loads (issue before any convert/MFMA) ----
    short8 G[2][2], T1[2][2], T2[2][2];
#pragma unroll
    for (int mi = 0; mi < 2; ++mi) {
        int row = mbase + mi * 16 + l15;
#pragma unroll
        for (int half = 0; half < 2; ++half) {
            size_t off = (size_t)row * 64 + half * 32 + koff;
            G[mi][half]  = *(const short8*)(gin + off);
            T1[mi][half] = *(const short8*)(gt1 + off);
            T2[mi][half] = *(const short8*)(gt2 + off);
        }
    }

    float bj0 = bias[nbase + l15];
    float bj1 = bias[nbase + 16 + l15];

    f32x4 acc[2][2];
#pragma unroll
    for (int mi = 0; mi < 2; ++mi)
#pragma unroll
        for (int ni = 0; ni < 2; ++ni)
#pragma unroll
            for (int r = 0; r < 4; ++r) acc[mi][ni][r] = 0.0f;

#pragma unroll
    for (int kt = 0; kt < 6; ++kt) {
        short8 Af[2];
#pragma unroll
        for (int mi = 0; mi < 2; ++mi) {
            short8 a;
            if (kt < 2) {
                a = G[mi][kt];
            } else if (kt < 4) {
                a = T1[mi][kt - 2];
            } else {
                short8 a2 = T2[mi][kt - 4];
                short8 ai = G[mi][kt - 4];
#pragma unroll
                for (int j = 0; j < 8; ++j)
                    a[j] = (short)f2b(fmaf(2.0f, b2f((u16)a2[j]), -b2f((u16)ai[j])));
            }
            Af[mi] = a;
        }
#pragma unroll
        for (int mi = 0; mi < 2; ++mi)
#pragma unroll
            for (int ni = 0; ni < 2; ++ni)
                acc[mi][ni] = __builtin_amdgcn_mfma_f32_16x16x32_bf16(
                    Af[mi], Bf[kt][ni], acc[mi][ni], 0, 0, 0);
    }

    // ---- epilogue: un-scale, bias, relu, single store ----
    float4 rsv[2], sv[2];
#pragma unroll
    for (int mi = 0; mi < 2; ++mi) {
        rsv[mi] = *(const float4*)(rsArr + mbase + mi * 16 + l4 * 4);
        if (!last) sv[mi] = *(const float4*)(sArr + mbase + mi * 16 + l4 * 4);
    }
#pragma unroll
    for (int mi = 0; mi < 2; ++mi)
#pragma unroll
        for (int r = 0; r < 4; ++r) {
            int node = mbase + mi * 16 + l4 * 4 + r;
            if (node >= N_NODES) continue;
            float rsr = ((const float*)&rsv[mi])[r];
#pragma unroll
            for (int ni = 0; ni < 2; ++ni) {
                int col = nbase + ni * 16 + l15;
                size_t o = (size_t)node * 64 + col;
                float v = fmaf(rsr, acc[mi][ni][r], (ni ? bj1 : bj0));
                v = fmaxf(v, 0.0f);
                if (last) {
                    outf[o] = v;
                } else {
                    float sr = ((const float*)&sv[mi])[r];
                    outg[o] = f2b(v * sr);
                }
            }
        }
}

extern "C" void kernel_launch(void* const* d_in, const int* in_sizes, int n_in,
                              void* d_out, int out_size, void* d_ws, size_t ws_size,
                              hipStream_t stream) {
    const float* x = (const float*)d_in[0];
    const int* ei = (const int*)d_in[1];
    const float* W = (const float*)d_in[2];   // [3,3,64,64]
    const float* b = (const float*)d_in[3];   // [3,64]
    float* out = (float*)d_out;

    const int* src = ei;
    const int* dst = ei + N_EDGES;

    const size_t NDP = (size_t)NPAD * D;
    const size_t CVSZ = (size_t)N_EDGES + 72 + (size_t)NB * BSLACK;  // padded cv entries

    char* w = (char*)d_ws;
    int*   cnt2   = (int*)w;        w += (size_t)512 * 4;
    int*   base2  = (int*)w;        w += (size_t)512 * 4;
    int*   curs2  = (int*)w;        w += (size_t)512 * 4;
    int*   rowptr = (int*)w;        w += (size_t)NPAD * 4;
    int*   rowend = (int*)w;        w += (size_t)NPAD * 4;
    float* sArr   = (float*)w;      w += (size_t)NPAD * 4;
    float* rsArr  = (float*)w;      w += (size_t)NPAD * 4;
    float* mArr   = (float*)w;      w += (size_t)NPAD * 4;
    u16*   Wb     = (u16*)w;        w += (size_t)72 * 512 * 2;
    int*   cv     = (int*)w;        w += ((CVSZ + 63) & ~(size_t)63) * 4;
    u16*   gA     = (u16*)w;        w += NDP * 2;
    u16*   gB     = (u16*)w;        w += NDP * 2;
    u16*   gt1    = (u16*)w;        w += NDP * 2;
    u16*   gt2    = (u16*)w;        w += NDP * 2;
    // partition buffers alias gt2/gB (dead after csr/degs; gt2 is never a
    // gather source and is fully rewritten by gather2 before cheb reads it;
    // gB is fully rewritten by cheb layer 0 before any consumer reads it)
    int*   dstPart = (int*)gt2;
    u16*   srcPart = (u16*)gB;

    int* baseD = base2;
    int* baseS = base2 + (NB + 1);
    int* cursD = curs2;
    int* cursS = curs2 + NB;

    // ---- CSR build (bucketed radix partition, LDS atomics, padded lists) ----
    hipMemsetAsync(cnt2, 0, (size_t)(2 * NB) * 4, stream);
    hist_kernel<<<304, 256, 0, stream>>>(src, dst, cnt2, N_EDGES);
    scanb_kernel<<<1, 256, 0, stream>>>(cnt2, base2, curs2);
    part_kernel<<<NCHUNK, 256, 0, stream>>>(src, dst, cursD, cursS, dstPart, srcPart, N_EDGES);
    csr_kernel<<<NB, 256, 0, stream>>>(baseD, dstPart, rowptr, rowend, cv);
    degs_kernel<<<NB, 256, 0, stream>>>(baseS, srcPart, sArr, rsArr, mArr);
    wprep_kernel<<<144, 256, 0, stream>>>(W, Wb);
    zrow_kernel<<<1, 256, 0, stream>>>(gA, gB, gt1);   // after csr/degs (aliasing)
    cvt_kernel<<<(int)(((size_t)N_NODES * D / 4 + 255) / 256), 256, 0, stream>>>(
        x, sArr, gA, (int)((size_t)N_NODES * D / 4));

    const int gatherBlocks = (N_NODES + 3) / 4;
    const int chebBlocks = NPAD / 64;   // 1568 one-tile blocks

    const u16* gin = gA;
    for (int l = 0; l < NUM_LAYERS; ++l) {
        gather_kernel<<<gatherBlocks, 256, 0, stream>>>(rowptr, rowend, cv, gin, mArr, gt1, N_NODES);
        gather_kernel<<<gatherBlocks, 256, 0, stream>>>(rowptr, rowend, cv, gt1, mArr, gt2, N_NODES);

        int last = (l == NUM_LAYERS - 1);
        u16* gout = (l == 0) ? gB : gA;   // ping-pong (unused when last)
        cheb_mfma_kernel<<<chebBlocks, 256, 0, stream>>>(
            gin, gt1, gt2, Wb + (size_t)l * 24 * 512, b + (size_t)l * D,
            rsArr, sArr, gout, out, last);
        gin = gout;
    }
}

// Round 14
// 287.480 us; speedup vs baseline: 1.6773x; 1.1354x over previous
//
#include <hip/hip_runtime.h>

#define N_NODES 100000
#define N_EDGES 1200000
#define D 64
#define NUM_LAYERS 3

#define NB 196          // coarse buckets
#define BSZ 512         // nodes per bucket (NB*BSZ = 100352 >= N_NODES)
#define NPAD (NB * BSZ) // padded node count (100352, multiple of 128)
#define CHUNK 4096      // edges per partition block
#define NCHUNK ((N_EDGES + CHUNK - 1) / CHUNK)   // 293
#define ZROW N_NODES    // dummy src row (zeroed) for list padding
#define BSLACK 3592     // per-bucket pad slack: 512*7 + 8 (alignment-safe)
#define CAP 8192        // fixed per-bucket edge capacity (mean 6123, 26 sigma)

typedef unsigned int uint;
typedef unsigned short u16;

using short8 = __attribute__((ext_vector_type(8))) short;
using f32x4  = __attribute__((ext_vector_type(4))) float;

static __device__ __forceinline__ float b2f(u16 u) {
    return __uint_as_float(((uint)u) << 16);
}
static __device__ __forceinline__ u16 f2b(float f) {
    uint u = __float_as_uint(f);
    return (u16)((u + 0x7FFFu + ((u >> 16) & 1u)) >> 16);
}

// ---- P1: partition edges into coarse buckets (LDS-staged chunks) ----
// cursors pre-initialized to b*CAP by wprep_kernel; no global scan needed.
__global__ __launch_bounds__(256) void part_kernel(const int* __restrict__ src,
        const int* __restrict__ dst, int* __restrict__ cursD, int* __restrict__ cursS,
        int* __restrict__ dstPart, u16* __restrict__ srcPart, int E) {
    __shared__ int eS[CHUNK], eT[CHUNK];
    __shared__ int hD[NB], hS[NB], bD[NB], bS[NB];
    int e0 = blockIdx.x * CHUNK;
    int n = min(CHUNK, E - e0);
    for (int i = threadIdx.x; i < NB; i += 256) { hD[i] = 0; hS[i] = 0; }
    for (int i = threadIdx.x; i < n; i += 256) { eS[i] = src[e0 + i]; eT[i] = dst[e0 + i]; }
    __syncthreads();
    for (int i = threadIdx.x; i < n; i += 256) {
        atomicAdd(&hD[((unsigned)eT[i]) >> 9], 1);
        atomicAdd(&hS[((unsigned)eS[i]) >> 9], 1);
    }
    __syncthreads();
    for (int i = threadIdx.x; i < NB; i += 256) {
        bD[i] = hD[i] ? atomicAdd(&cursD[i], hD[i]) : 0;
        bS[i] = hS[i] ? atomicAdd(&cursS[i], hS[i]) : 0;
        hD[i] = 0; hS[i] = 0;          // reuse as local cursors
    }
    __syncthreads();
    for (int i = threadIdx.x; i < n; i += 256) {
        int s = eS[i], t = eT[i];
        int kb = ((unsigned)t) >> 9;
        int pos = bD[kb] + atomicAdd(&hD[kb], 1);
        if (pos < (kb + 1) * CAP) dstPart[pos] = ((t & 511) << 20) | s;
        kb = ((unsigned)s) >> 9;
        pos = bS[kb] + atomicAdd(&hS[kb], 1);
        if (pos < (kb + 1) * CAP) srcPart[pos] = (u16)(s & 511);
    }
}

// ---- P2a: per-bucket CSR, lists padded to multiples of 8 (dummy = ZROW) ----
__global__ __launch_bounds__(256) void csr_kernel(const int* __restrict__ cursD,
        const int* __restrict__ dstPart, int* __restrict__ rowptr,
        int* __restrict__ rowend, int* __restrict__ cv) {
    __shared__ int cnt[BSZ], curs[BSZ], psum[256];
    int b = blockIdx.x, t = threadIdx.x;
    int node0 = b * BSZ;
    int eb = b * CAP;
    int ee = min(cursD[b], (b + 1) * CAP);
    int padbase = eb + b * BSLACK;   // eb is 8-aligned (CAP mult of 8)
    for (int i = t; i < BSZ; i += 256) cnt[i] = 0;
    __syncthreads();
    for (int e = eb + t; e < ee; e += 256)
        atomicAdd(&cnt[((unsigned)dstPart[e]) >> 20], 1);
    __syncthreads();
    int c0 = cnt[2 * t], c1 = cnt[2 * t + 1];
    int p0 = (c0 + 7) & ~7, p1 = (c1 + 7) & ~7;
    psum[t] = p0 + p1;
    __syncthreads();
    for (int off = 1; off < 256; off <<= 1) {
        int u = (t >= off) ? psum[t - off] : 0;
        __syncthreads();
        psum[t] += u;
        __syncthreads();
    }
    int excl = psum[t] - p0 - p1;
    int start0 = padbase + excl;
    int start1 = start0 + p0;
    curs[2 * t] = start0;
    curs[2 * t + 1] = start1;
    int n0 = node0 + 2 * t;
    if (n0 < N_NODES)     { rowptr[n0]     = start0; rowend[n0]     = start0 + p0; }
    if (n0 + 1 < N_NODES) { rowptr[n0 + 1] = start1; rowend[n0 + 1] = start1 + p1; }
    __syncthreads();
    for (int e = eb + t; e < ee; e += 256) {
        int p = dstPart[e];
        int loc = ((unsigned)p) >> 20;
        int pos = atomicAdd(&curs[loc], 1);
        cv[pos] = p & 0xFFFFF;
    }
    __syncthreads();
    // fill dummy tail slots
    for (int q = c0; q < p0; ++q) cv[start0 + q] = ZROW;
    for (int q = c1; q < p1; ++q) cv[start1 + q] = ZROW;
}

// ---- P2b: per-bucket src-degree histogram -> s, rs, m arrays ----
// s[r]  = deg>0 ? 1/sqrt(deg) : 1   (feature row scale)
// rs[r] = 1/s[r]                     (epilogue un-scale)
// m[r]  = deg>0 ? -1/deg : 0        (gather output scale = -s*dinv)
__global__ __launch_bounds__(256) void degs_kernel(const int* __restrict__ cursS,
        const u16* __restrict__ srcPart, float* __restrict__ sArr,
        float* __restrict__ rsArr, float* __restrict__ mArr) {
    __shared__ int cnt[BSZ];
    int b = blockIdx.x, t = threadIdx.x;
    int eb = b * CAP;
    int ee = min(cursS[b], (b + 1) * CAP);
    for (int i = t; i < BSZ; i += 256) cnt[i] = 0;
    __syncthreads();
    for (int e = eb + t; e < ee; e += 256)
        atomicAdd(&cnt[srcPart[e]], 1);
    __syncthreads();
    for (int i = t; i < BSZ; i += 256) {
        int node = b * BSZ + i;
        if (node < N_NODES) {
            int d = cnt[i];
            float fd = (float)d;
            sArr[node]  = (d > 0) ? rsqrtf(fd) : 1.0f;
            rsArr[node] = (d > 0) ? sqrtf(fd) : 1.0f;
            mArr[node]  = (d > 0) ? (-1.0f / fd) : 0.0f;
        }
    }
}

// ---- W -> bf16 fragments in MFMA order + cursor init + ZROW zeroing ----
// fid = ((l*2 + wn)*6 + kt)*2 + ni ; element = fid*512 + lane*8 + j
// skip-fold: for l>0 add identity
__global__ __launch_bounds__(256) void wprep_kernel(const float* __restrict__ W,
        u16* __restrict__ Wb, int* __restrict__ curs2,
        u16* __restrict__ za, u16* __restrict__ zb, u16* __restrict__ zc) {
    if (blockIdx.x == 0) {
        for (int k = threadIdx.x; k < 2 * NB; k += 256)
            curs2[k] = (k < NB ? k : k - NB) * CAP;
        if (threadIdx.x < 192) {
            u16* buf = (threadIdx.x < 64) ? za : (threadIdx.x < 128) ? zb : zc;
            buf[(size_t)ZROW * D + (threadIdx.x & 63)] = 0;
        }
    }
    int i = blockIdx.x * 256 + threadIdx.x;
    if (i >= 72 * 512) return;
    int j = i & 7;
    int lane = (i >> 3) & 63;
    int fid = i >> 9;
    int ni = fid & 1;
    int t = fid >> 1;
    int kt = t % 6;
    int t2 = t / 6;
    int wn = t2 & 1;
    int l = t2 >> 1;
    int k = kt * 32 + (lane >> 4) * 8 + j;
    int col = wn * 32 + ni * 16 + (lane & 15);
    float v = W[((size_t)l * 192 + k) * 64 + col];
    if (l > 0 && k == col) v += 1.0f;   // skip folded into W0
    Wb[i] = f2b(v);
}

// ---- x -> g0 = s * x (bf16, row-major) ----
__global__ __launch_bounds__(256) void cvt_kernel(const float* __restrict__ x,
        const float* __restrict__ sArr, u16* __restrict__ g0, int nvec) {
    int i = blockIdx.x * blockDim.x + threadIdx.x;
    if (i >= nvec) return;
    float4 v = ((const float4*)x)[i];
    float dv = sArr[i >> 4];
    uint2 b;
    b.x = (uint)f2b(v.x * dv) | ((uint)f2b(v.y * dv) << 16);
    b.y = (uint)f2b(v.z * dv) | ((uint)f2b(v.w * dv) << 16);
    ((uint2*)g0)[i] = b;
}

// ---- per-node gather helper: sum of g[src] rows over one padded list ----
static __device__ __forceinline__ float gather_one(const int* __restrict__ cv,
        const u16* __restrict__ g, int lane, int p, int pe) {
    float a0 = 0.f, a1 = 0.f, a2 = 0.f, a3 = 0.f,
          a4 = 0.f, a5 = 0.f, a6 = 0.f, a7 = 0.f;
    if (pe - p == 16) {
        int4 c0 = *(const int4*)(cv + p);
        int4 c1 = *(const int4*)(cv + p + 4);
        int4 c2 = *(const int4*)(cv + p + 8);
        int4 c3 = *(const int4*)(cv + p + 12);
        float v0  = b2f(g[(size_t)c0.x * D + lane]);
        float v1  = b2f(g[(size_t)c0.y * D + lane]);
        float v2  = b2f(g[(size_t)c0.z * D + lane]);
        float v3  = b2f(g[(size_t)c0.w * D + lane]);
        float v4  = b2f(g[(size_t)c1.x * D + lane]);
        float v5  = b2f(g[(size_t)c1.y * D + lane]);
        float v6  = b2f(g[(size_t)c1.z * D + lane]);
        float v7  = b2f(g[(size_t)c1.w * D + lane]);
        float v8  = b2f(g[(size_t)c2.x * D + lane]);
        float v9  = b2f(g[(size_t)c2.y * D + lane]);
        float v10 = b2f(g[(size_t)c2.z * D + lane]);
        float v11 = b2f(g[(size_t)c2.w * D + lane]);
        float v12 = b2f(g[(size_t)c3.x * D + lane]);
        float v13 = b2f(g[(size_t)c3.y * D + lane]);
        float v14 = b2f(g[(size_t)c3.z * D + lane]);
        float v15 = b2f(g[(size_t)c3.w * D + lane]);
        a0 = (v0 + v8);  a1 = (v1 + v9);  a2 = (v2 + v10); a3 = (v3 + v11);
        a4 = (v4 + v12); a5 = (v5 + v13); a6 = (v6 + v14); a7 = (v7 + v15);
    } else if (pe > p) {
        int4 ca = *(const int4*)(cv + p);
        int4 cb = *(const int4*)(cv + p + 4);
        for (;;) {
            int np = p + 8;
            bool more = np < pe;
            int4 na, nb;
            if (more) {                    // prefetch next round's cv early
                na = *(const int4*)(cv + np);
                nb = *(const int4*)(cv + np + 4);
            }
            a0 += b2f(g[(size_t)ca.x * D + lane]);
            a1 += b2f(g[(size_t)ca.y * D + lane]);
            a2 += b2f(g[(size_t)ca.z * D + lane]);
            a3 += b2f(g[(size_t)ca.w * D + lane]);
            a4 += b2f(g[(size_t)cb.x * D + lane]);
            a5 += b2f(g[(size_t)cb.y * D + lane]);
            a6 += b2f(g[(size_t)cb.z * D + lane]);
            a7 += b2f(g[(size_t)cb.w * D + lane]);
            if (!more) break;
            ca = na; cb = nb; p = np;
        }
    }
    return ((a0 + a1) + (a2 + a3)) + ((a4 + a5) + (a6 + a7));
}

// ---- propagate (scaled space): outg[t] = m[t] * sum_e g[src_e] ----
// TWO adjacent nodes per wave: both-16 fast path issues 8 cv + 32 row loads
// back-to-back (2x memory-level parallelism); mixed lengths fall back to
// sequential per-node processing.
__global__ __launch_bounds__(256) void gather_kernel(const int* __restrict__ rowptr,
        const int* __restrict__ rowend, const int* __restrict__ cv,
        const u16* __restrict__ g, const float* __restrict__ mArr,
        u16* __restrict__ outg, int n) {
    int lane = threadIdx.x & 63;
    int nA = __builtin_amdgcn_readfirstlane((int)(blockIdx.x * 8) + ((threadIdx.x >> 6) << 1));
    if (nA >= n) return;
    const int nB = nA + 1;
    const bool hasB = nB < n;
    int p1 = rowptr[nA], pe1 = rowend[nA];
    int p2 = p1, pe2 = p1;                 // empty default
    if (hasB) { p2 = rowptr[nB]; pe2 = rowend[nB]; }
    float sumA, sumB = 0.0f;

    if ((pe1 - p1 == 16) && (pe2 - p2 == 16)) {
        int4 a0 = *(const int4*)(cv + p1);
        int4 a1 = *(const int4*)(cv + p1 + 4);
        int4 a2 = *(const int4*)(cv + p1 + 8);
        int4 a3 = *(const int4*)(cv + p1 + 12);
        int4 b0 = *(const int4*)(cv + p2);
        int4 b1 = *(const int4*)(cv + p2 + 4);
        int4 b2 = *(const int4*)(cv + p2 + 8);
        int4 b3 = *(const int4*)(cv + p2 + 12);
        float uA0  = b2f(g[(size_t)a0.x * D + lane]);
        float uA1  = b2f(g[(size_t)a0.y * D + lane]);
        float uA2  = b2f(g[(size_t)a0.z * D + lane]);
        float uA3  = b2f(g[(size_t)a0.w * D + lane]);
        float uA4  = b2f(g[(size_t)a1.x * D + lane]);
        float uA5  = b2f(g[(size_t)a1.y * D + lane]);
        float uA6  = b2f(g[(size_t)a1.z * D + lane]);
        float uA7  = b2f(g[(size_t)a1.w * D + lane]);
        float uA8  = b2f(g[(size_t)a2.x * D + lane]);
        float uA9  = b2f(g[(size_t)a2.y * D + lane]);
        float uA10 = b2f(g[(size_t)a2.z * D + lane]);
        float uA11 = b2f(g[(size_t)a2.w * D + lane]);
        float uA12 = b2f(g[(size_t)a3.x * D + lane]);
        float uA13 = b2f(g[(size_t)a3.y * D + lane]);
        float uA14 = b2f(g[(size_t)a3.z * D + lane]);
        float uA15 = b2f(g[(size_t)a3.w * D + lane]);
        float uB0  = b2f(g[(size_t)b0.x * D + lane]);
        float uB1  = b2f(g[(size_t)b0.y * D + lane]);
        float uB2  = b2f(g[(size_t)b0.z * D + lane]);
        float uB3  = b2f(g[(size_t)b0.w * D + lane]);
        float uB4  = b2f(g[(size_t)b1.x * D + lane]);
        float uB5  = b2f(g[(size_t)b1.y * D + lane]);
        float uB6  = b2f(g[(size_t)b1.z * D + lane]);
        float uB7  = b2f(g[(size_t)b1.w * D + lane]);
        float uB8  = b2f(g[(size_t)b2.x * D + lane]);
        float uB9  = b2f(g[(size_t)b2.y * D + lane]);
        float uB10 = b2f(g[(size_t)b2.z * D + lane]);
        float uB11 = b2f(g[(size_t)b2.w * D + lane]);
        float uB12 = b2f(g[(size_t)b3.x * D + lane]);
        float uB13 = b2f(g[(size_t)b3.y * D + lane]);
        float uB14 = b2f(g[(size_t)b3.z * D + lane]);
        float uB15 = b2f(g[(size_t)b3.w * D + lane]);
        sumA = (((uA0 + uA8) + (uA1 + uA9)) + ((uA2 + uA10) + (uA3 + uA11)))
             + (((uA4 + uA12) + (uA5 + uA13)) + ((uA6 + uA14) + (uA7 + uA15)));
        sumB = (((uB0 + uB8) + (uB1 + uB9)) + ((uB2 + uB10) + (uB3 + uB11)))
             + (((uB4 + uB12) + (uB5 + uB13)) + ((uB6 + uB14) + (uB7 + uB15)));
    } else {
        sumA = gather_one(cv, g, lane, p1, pe1);
        sumB = gather_one(cv, g, lane, p2, pe2);
    }

    outg[(size_t)nA * D + lane] = f2b(mArr[nA] * sumA);
    if (hasB)
        outg[(size_t)nB * D + lane] = f2b(mArr[nB] * sumB);
}

// ---- MFMA epilogue (scaled space): raw = [g|gt1|2*gt2-g] @ Wcat', then
// v = rs[r]*raw + bias (skip folded in W'), relu; store g_next = s[r]*v
// (or f32 v for the last layer). All operands bf16 row-major.
__global__ __launch_bounds__(256) void cheb_mfma_kernel(
        const u16* __restrict__ gin, const u16* __restrict__ gt1,
        const u16* __restrict__ gt2, const u16* __restrict__ Wbl,
        const float* __restrict__ bias, const float* __restrict__ rsArr,
        const float* __restrict__ sArr,
        u16* __restrict__ outg, float* __restrict__ outf, int last) {
    const int tid = threadIdx.x;
    const int lane = tid & 63;
    const int w = tid >> 6;
    const int wm = w & 1, wn = w >> 1;
    const int l15 = lane & 15;
    const int l4 = lane >> 4;        // 0..3
    const int koff = l4 * 8;

    const int mbase = blockIdx.x * 64 + wm * 32;
    const int nbase = wn * 32;

    // ---- fragment-ordered weight preload: 12 x 16B vector loads ----
    short8 Bf[6][2];
#pragma unroll
    for (int kt = 0; kt < 6; ++kt)
#pragma unroll
        for (int ni = 0; ni < 2; ++ni)
            Bf[kt][ni] = *(const short8*)(Wbl + (size_t)(((wn * 6 + kt) * 2) + ni) * 512 + lane * 8);

    // ---- hoist ALL A-source loads (issue before any convert/MFMA) ----
    short8 G[2][2], T1[2][2], T2[2][2];
#pragma unroll
    for (int mi = 0; mi < 2; ++mi) {
        int row = mbase + mi * 16 + l15;
#pragma unroll
        for (int half = 0; half < 2; ++half) {
            size_t off = (size_t)row * 64 + half * 32 + koff;
            G[mi][half]  = *(const short8*)(gin + off);
            T1[mi][half] = *(const short8*)(gt1 + off);
            T2[mi][half] = *(const short8*)(gt2 + off);
        }
    }

    float bj0 = bias[nbase + l15];
    float bj1 = bias[nbase + 16 + l15];

    f32x4 acc[2][2];
#pragma unroll
    for (int mi = 0; mi < 2; ++mi)
#pragma unroll
        for (int ni = 0; ni < 2; ++ni)
#pragma unroll
            for (int r = 0; r < 4; ++r) acc[mi][ni][r] = 0.0f;

#pragma unroll
    for (int kt = 0; kt < 6; ++kt) {
        short8 Af[2];
#pragma unroll
        for (int mi = 0; mi < 2; ++mi) {
            short8 a;
            if (kt < 2) {
                a = G[mi][kt];
            } else if (kt < 4) {
                a = T1[mi][kt - 2];
            } else {
                short8 a2 = T2[mi][kt - 4];
                short8 ai = G[mi][kt - 4];
#pragma unroll
                for (int j = 0; j < 8; ++j)
                    a[j] = (short)f2b(fmaf(2.0f, b2f((u16)a2[j]), -b2f((u16)ai[j])));
            }
            Af[mi] = a;
        }
#pragma unroll
        for (int mi = 0; mi < 2; ++mi)
#pragma unroll
            for (int ni = 0; ni < 2; ++ni)
                acc[mi][ni] = __builtin_amdgcn_mfma_f32_16x16x32_bf16(
                    Af[mi], Bf[kt][ni], acc[mi][ni], 0, 0, 0);
    }

    // ---- epilogue: un-scale, bias, relu, single store ----
    float4 rsv[2], sv[2];
#pragma unroll
    for (int mi = 0; mi < 2; ++mi) {
        rsv[mi] = *(const float4*)(rsArr + mbase + mi * 16 + l4 * 4);
        if (!last) sv[mi] = *(const float4*)(sArr + mbase + mi * 16 + l4 * 4);
    }
#pragma unroll
    for (int mi = 0; mi < 2; ++mi)
#pragma unroll
        for (int r = 0; r < 4; ++r) {
            int node = mbase + mi * 16 + l4 * 4 + r;
            if (node >= N_NODES) continue;
            float rsr = ((const float*)&rsv[mi])[r];
#pragma unroll
            for (int ni = 0; ni < 2; ++ni) {
                int col = nbase + ni * 16 + l15;
                size_t o = (size_t)node * 64 + col;
                float v = fmaf(rsr, acc[mi][ni][r], (ni ? bj1 : bj0));
                v = fmaxf(v, 0.0f);
                if (last) {
                    outf[o] = v;
                } else {
                    float sr = ((const float*)&sv[mi])[r];
                    outg[o] = f2b(v * sr);
                }
            }
        }
}

extern "C" void kernel_launch(void* const* d_in, const int* in_sizes, int n_in,
                              void* d_out, int out_size, void* d_ws, size_t ws_size,
                              hipStream_t stream) {
    const float* x = (const float*)d_in[0];
    const int* ei = (const int*)d_in[1];
    const float* W = (const float*)d_in[2];   // [3,3,64,64]
    const float* b = (const float*)d_in[3];   // [3,64]
    float* out = (float*)d_out;

    const int* src = ei;
    const int* dst = ei + N_EDGES;

    const size_t NDP = (size_t)NPAD * D;
    const size_t CVSZ = (size_t)NB * (CAP + BSLACK) + 64;  // padded cv entries

    char* w = (char*)d_ws;
    int*   curs2  = (int*)w;        w += (size_t)512 * 4;
    int*   rowptr = (int*)w;        w += (size_t)NPAD * 4;
    int*   rowend = (int*)w;        w += (size_t)NPAD * 4;
    float* sArr   = (float*)w;      w += (size_t)NPAD * 4;
    float* rsArr  = (float*)w;      w += (size_t)NPAD * 4;
    float* mArr   = (float*)w;      w += (size_t)NPAD * 4;
    u16*   Wb     = (u16*)w;        w += (size_t)72 * 512 * 2;
    int*   cv     = (int*)w;        w += ((CVSZ + 63) & ~(size_t)63) * 4;
    u16*   gA     = (u16*)w;        w += NDP * 2;
    u16*   gB     = (u16*)w;        w += NDP * 2;
    u16*   gt1    = (u16*)w;        w += NDP * 2;
    u16*   gt2    = (u16*)w;        w += NDP * 2;
    // partition buffers alias gt2/gB (dead after csr/degs; gt2 is never a
    // gather source and is fully rewritten by gather2 before cheb reads it;
    // gB is fully rewritten by cheb layer 0 before any consumer reads it;
    // ZROW row of gB at 12.8MB offset is beyond srcPart's 3.2MB)
    int*   dstPart = (int*)gt2;     // NB*CAP ints = 6.4 MB <= 12.8 MB
    u16*   srcPart = (u16*)gB;      // NB*CAP u16 = 3.2 MB

    int* cursD = curs2;
    int* cursS = curs2 + NB;

    // ---- build: wprep(+cursor init+zrow) -> part -> csr -> degs -> cvt ----
    wprep_kernel<<<144, 256, 0, stream>>>(W, Wb, curs2, gA, gB, gt1);
    part_kernel<<<NCHUNK, 256, 0, stream>>>(src, dst, cursD, cursS, dstPart, srcPart, N_EDGES);
    csr_kernel<<<NB, 256, 0, stream>>>(cursD, dstPart, rowptr, rowend, cv);
    degs_kernel<<<NB, 256, 0, stream>>>(cursS, srcPart, sArr, rsArr, mArr);
    cvt_kernel<<<(int)(((size_t)N_NODES * D / 4 + 255) / 256), 256, 0, stream>>>(
        x, sArr, gA, (int)((size_t)N_NODES * D / 4));

    const int gatherBlocks = (N_NODES + 7) / 8;   // 2 nodes per wave
    const int chebBlocks = NPAD / 64;             // 1568 one-tile blocks

    const u16* gin = gA;
    for (int l = 0; l < NUM_LAYERS; ++l) {
        gather_kernel<<<gatherBlocks, 256, 0, stream>>>(rowptr, rowend, cv, gin, mArr, gt1, N_NODES);
        gather_kernel<<<gatherBlocks, 256, 0, stream>>>(rowptr, rowend, cv, gt1, mArr, gt2, N_NODES);

        int last = (l == NUM_LAYERS - 1);
        u16* gout = (l == 0) ? gB : gA;   // ping-pong (unused when last)
        cheb_mfma_kernel<<<chebBlocks, 256, 0, stream>>>(
            gin, gt1, gt2, Wb + (size_t)l * 24 * 512, b + (size_t)l * D,
            rsArr, sArr, gout, out, last);
        gin = gout;
    }
}